// Round 5
// baseline (409.390 us; speedup 1.0000x reference)
//
#include <hip/hip_runtime.h>
#include <hip/hip_bf16.h>
#include <math.h>

// Problem constants
#define R_   8192    // B*S rows
#define DM   1024    // d_model
#define DFF  4096    // d_ff
#define NP   64      // n_patterns
#define KN   8       // K neurons

typedef __bf16 bf16x8 __attribute__((ext_vector_type(8)));
typedef float  f32x4  __attribute__((ext_vector_type(4)));

__device__ __forceinline__ unsigned short f2bf(float f) {
  union { float f; unsigned u; } v; v.f = f;
  unsigned u = v.u;
  return (unsigned short)((u + 0x7FFFu + ((u >> 16) & 1u)) >> 16);
}

__device__ __forceinline__ float dot4(const float4 a, const float4 b) {
  return a.x * b.x + a.y * b.y + a.z * b.z + a.w * b.w;
}

__device__ __forceinline__ void fma4(float4& a, float w, const float4 s) {
  a.x += w * s.x; a.y += w * s.y; a.z += w * s.z; a.w += w * s.w;
}

// ---------------------------------------------------------------- f32 -> bf16
__global__ __launch_bounds__(256) void cvt_bf16_kernel(
    const float* __restrict__ in, unsigned short* __restrict__ out, int n8) {
  int i = blockIdx.x * 256 + threadIdx.x;
  if (i >= n8) return;
  const float4* p = (const float4*)in + (size_t)i * 2;
  float4 a = p[0], b = p[1];
  uint4 r;
  r.x = (unsigned)f2bf(a.x) | ((unsigned)f2bf(a.y) << 16);
  r.y = (unsigned)f2bf(a.z) | ((unsigned)f2bf(a.w) << 16);
  r.z = (unsigned)f2bf(b.x) | ((unsigned)f2bf(b.y) << 16);
  r.w = (unsigned)f2bf(b.z) | ((unsigned)f2bf(b.w) << 16);
  ((uint4*)out)[i] = r;
}

// -------------------------------------------------------------- v materialize
__global__ __launch_bounds__(256) void vcomp_kernel(
    const float* __restrict__ sn,    // [R_][8][1024]
    const float* __restrict__ tw,    // [R_][8]
    float* __restrict__ v)           // [R_][1024]
{
  const int r = blockIdx.x;
  const int t = threadIdx.x;
  float w[KN];
#pragma unroll
  for (int k = 0; k < KN; ++k) w[k] = tw[(size_t)r * KN + k];
  const float* base = sn + (size_t)r * (KN * DM) + t * 4;
  float4 a = {0.f, 0.f, 0.f, 0.f};
#pragma unroll
  for (int k = 0; k < KN; ++k) fma4(a, w[k], *(const float4*)(base + k * DM));
  *(float4*)(v + (size_t)r * DM + t * 4) = a;
}

// ------------------------------------------------- pattern scores/topk/softmax
__global__ __launch_bounds__(256, 2) void score_kernel(
    const float* __restrict__ v,     // [R_][1024]
    const float* __restrict__ pq,    // [64][1024]
    int*   __restrict__ out_idx,     // [R_][4]
    float* __restrict__ out_w)       // [R_][4]
{
  const int lane = threadIdx.x & 63;
  const int wave = threadIdx.x >> 6;
  const int pos0 = (blockIdx.x * 4 + wave) * 4;

  float4 vr[4][4];
#pragma unroll
  for (int p = 0; p < 4; ++p) {
    const float4* s = (const float4*)(v + (size_t)(pos0 + p) * DM + lane * 16);
    vr[p][0] = s[0]; vr[p][1] = s[1]; vr[p][2] = s[2]; vr[p][3] = s[3];
  }

  float sreg[4];
#pragma unroll 1
  for (int pat = 0; pat < NP; ++pat) {
    const float4* q = (const float4*)(pq + pat * DM + lane * 16);
    const float4 q0 = q[0], q1 = q[1], q2 = q[2], q3 = q[3];
    float part[4];
#pragma unroll
    for (int p = 0; p < 4; ++p)
      part[p] = dot4(q0, vr[p][0]) + dot4(q1, vr[p][1]) +
                dot4(q2, vr[p][2]) + dot4(q3, vr[p][3]);
#pragma unroll
    for (int off = 32; off >= 1; off >>= 1) {
#pragma unroll
      for (int p = 0; p < 4; ++p)
        part[p] += __shfl_xor(part[p], off, 64);
    }
    if (lane == pat) {
#pragma unroll
      for (int p = 0; p < 4; ++p) sreg[p] = part[p] * 0.03125f; // /sqrt(1024)
    }
  }

#pragma unroll
  for (int p = 0; p < 4; ++p) {
    float cur = sreg[p];
    float m0, m1, m2, m3; int i0, i1, i2, i3;
#define ARGMAX_STEP(MV, MI)                                   \
    {                                                         \
      float bv = cur; int bi = lane;                          \
      _Pragma("unroll")                                       \
      for (int off = 32; off >= 1; off >>= 1) {               \
        float ov = __shfl_xor(bv, off, 64);                   \
        int   oi = __shfl_xor(bi, off, 64);                   \
        if (ov > bv || (ov == bv && oi < bi)) { bv = ov; bi = oi; } \
      }                                                       \
      MV = bv; MI = bi;                                       \
      if (lane == bi) cur = -3.0e38f;                         \
    }
    ARGMAX_STEP(m0, i0) ARGMAX_STEP(m1, i1) ARGMAX_STEP(m2, i2) ARGMAX_STEP(m3, i3)
#undef ARGMAX_STEP
    const float e1 = __expf(m1 - m0), e2 = __expf(m2 - m0), e3 = __expf(m3 - m0);
    const float inv = 1.f / (1.f + e1 + e2 + e3);
    if (lane < 4) {
      const int r = pos0 + p;
      const int myi = (lane == 0) ? i0 : (lane == 1) ? i1 : (lane == 2) ? i2 : i3;
      const float mye = (lane == 0) ? 1.f : (lane == 1) ? e1 : (lane == 2) ? e2 : e3;
      out_idx[r * 4 + lane] = myi;
      out_w[r * 4 + lane] = mye * inv;
    }
  }
}

// ------------------------------------------------------------ GEMM machinery
__device__ __forceinline__ void gll16(const void* g, void* l) {
  __builtin_amdgcn_global_load_lds(
      (const __attribute__((address_space(1))) unsigned int*)g,
      (__attribute__((address_space(3))) unsigned int*)l, 16, 0, 0);
}

// 8-phase-style schedule (m201 template, BK=64, 512 thr / 8 waves).
// LDS per buffer: A tile rows*128B + B tile rows*128B; 2 buffers (dbuf by kt).
// XOR swizzle: element (row, 16B-slot k of 8) stored at slot k^(row&7).
//   writer (global_load_lds is linear): lane pre-swizzles global slot
//   (l&7)^(l>>3)  [row&7 == l>>3 for the staging map row = c*64+wid*8+(l>>3)]
//   reader: slot' = (4*ks + (l>>4)) ^ (l&7)   [row&7 == l&7 for frag rows]
//   -> 2-way bank spread per 16-lane group (free).
// Phase = {ds_read frags ; stage next-tile half(s) ; [vmcnt(0) at tile end]}
//         -> barrier -> lgkm(0) -> setprio(1) 16 MFMA setprio(0) -> barrier.
// Ledger: stages write buf^1 (its last reads drained >=1 barrier earlier);
// tile kt+1 reads begin only after kt's q-last vmcnt(0)+barrier.

#define RD4(D, P)                                                           \
  { _Pragma("unroll") for (int i_ = 0; i_ < 4; ++i_)                        \
      D[i_] = *(const bf16x8*)((P) + i_ * 2048); }

#define STAGEH(GB, LOFF)                                                    \
  { gll16((GB) + soff0, smem + (LOFF) + wid * 1024);                        \
    gll16((GB) + soff1, smem + (LOFF) + 8192 + wid * 1024); }

#define PHSYNC(DRAIN)                                                       \
  __builtin_amdgcn_sched_barrier(0);                                        \
  if (DRAIN) asm volatile("s_waitcnt vmcnt(0)" ::: "memory");               \
  __builtin_amdgcn_s_barrier();                                             \
  asm volatile("s_waitcnt lgkmcnt(0)" ::: "memory");                        \
  __builtin_amdgcn_sched_barrier(0);                                        \
  __builtin_amdgcn_s_setprio(1);

#define PHEND                                                               \
  __builtin_amdgcn_s_setprio(0);                                            \
  __builtin_amdgcn_s_barrier();                                             \
  __builtin_amdgcn_sched_barrier(0);

#define MF16(MO, AF, BF)                                                    \
  _Pragma("unroll") for (int m_ = 0; m_ < 4; ++m_)                          \
  _Pragma("unroll") for (int n_ = 0; n_ < 4; ++n_)                          \
    acc[(MO) + m_][n_] = __builtin_amdgcn_mfma_f32_16x16x32_bf16(           \
        AF[m_], BF[n_], acc[(MO) + m_][n_], 0, 0, 0);

// ---- GEMM1: H[8192][4096] = gelu_gate(xb[8192][1024] @ uwb[4096][1024]^T)
// tile 256x256, waves 2x4 (wave out 128x64), NT=16, LDS 2*64KB.
__global__ __launch_bounds__(512, 2) void gemm1_kernel(
    const unsigned short* __restrict__ A,
    const unsigned short* __restrict__ Bm,
    const float* __restrict__ bias,
    const int*   __restrict__ pidx,
    const float* __restrict__ pwt,
    const float* __restrict__ gates,
    unsigned short* __restrict__ H)
{
  extern __shared__ char smem[];
  constexpr int K_ = 1024, NT = 16;
  const int tid = threadIdx.x, lane = tid & 63, wid = tid >> 6;
  const int wr = wid >> 2, wc = wid & 3;
  const int cpx = gridDim.x >> 3;
  const int swzb = ((int)blockIdx.x & 7) * cpx + ((int)blockIdx.x >> 3);
  const int brow = swzb >> 4, bcol = swzb & 15;

  const unsigned short* Ab = A  + (size_t)brow * 256 * K_;
  const unsigned short* Bb = Bm + (size_t)bcol * 256 * K_;

  const int soff0 = (wid * 8 + (lane >> 3)) * K_ + ((lane & 7) ^ (lane >> 3)) * 8;
  const int soff1 = soff0 + 64 * K_;
  const int paoff = wr * 16384 + (lane & 15) * 128;
  const int pboff = 32768 + (wc >> 1) * 16384 + (wc & 1) * 8192 + (lane & 15) * 128;
  const int sw0 = ((lane >> 4) ^ (lane & 7)) * 16;
  const int sw1 = ((4 + (lane >> 4)) ^ (lane & 7)) * 16;

  f32x4 acc[8][4];
#pragma unroll
  for (int m = 0; m < 8; ++m)
#pragma unroll
    for (int n = 0; n < 4; ++n) acc[m][n] = (f32x4){0.f, 0.f, 0.f, 0.f};

  // prologue: stage tile 0 into buf0
  STAGEH(Ab,            0)
  STAGEH(Ab + 128 * K_, 16384)
  STAGEH(Bb,            32768)
  STAGEH(Bb + 128 * K_, 49152)
  asm volatile("s_waitcnt vmcnt(0)" ::: "memory");
  __builtin_amdgcn_s_barrier();

#define KT1_BODY(BB, SB, GUARD, KT)                                         \
  {                                                                         \
    const char* pa = smem + (BB) + paoff;                                   \
    const char* pb = smem + (BB) + pboff;                                   \
    const unsigned short* At = Ab + ((KT) + 1) * 64;                        \
    const unsigned short* Bt = Bb + ((KT) + 1) * 64;                        \
    bf16x8 af[4], bks[4];                                                   \
    /* q0: A(mh0,ks0)+B(ks0); stage next A0,A1 */                           \
    RD4(af, pa + sw0) RD4(bks, pb + sw0)                                    \
    if (GUARD) { STAGEH(At, (SB) + 0) STAGEH(At + 128 * K_, (SB) + 16384) } \
    PHSYNC(0) MF16(0, af, bks) PHEND                                        \
    /* q1: A(mh1,ks0); stage next B0 */                                     \
    RD4(af, pa + 8192 + sw0)                                                \
    if (GUARD) { STAGEH(Bt, (SB) + 32768) }                                 \
    PHSYNC(0) MF16(4, af, bks) PHEND                                        \
    /* q2: A(mh0,ks1)+B(ks1); stage next B1 */                              \
    RD4(af, pa + sw1) RD4(bks, pb + sw1)                                    \
    if (GUARD) { STAGEH(Bt + 128 * K_, (SB) + 49152) }                      \
    PHSYNC(0) MF16(0, af, bks) PHEND                                        \
    /* q3: A(mh1,ks1); drain */                                             \
    RD4(af, pa + 8192 + sw1)                                                \
    PHSYNC(1) MF16(4, af, bks) PHEND                                        \
  }

#pragma unroll 1
  for (int k2 = 0; k2 < NT / 2; ++k2) {
    const int kt0 = k2 * 2;
    KT1_BODY(0,     65536, true,             kt0)
    KT1_BODY(65536, 0,     (k2 < NT/2 - 1),  kt0 + 1)
  }
#undef KT1_BODY

  // epilogue: C/D layout col = lane&15, row = (lane>>4)*4 + j
  const int crow0 = brow * 256 + wr * 128;
  const int ccol0 = bcol * 256 + wc * 64 + (lane & 15);
  const int rsub  = (lane >> 4) * 4;
#pragma unroll
  for (int m = 0; m < 8; ++m) {
    const int rbase = crow0 + m * 16 + rsub;
    int   ia[4][4];
    float wa[4][4];
#pragma unroll
    for (int j = 0; j < 4; ++j) {
      const int4   iq = *(const int4*)(pidx + (size_t)(rbase + j) * 4);
      const float4 wq = *(const float4*)(pwt + (size_t)(rbase + j) * 4);
      ia[j][0] = iq.x; ia[j][1] = iq.y; ia[j][2] = iq.z; ia[j][3] = iq.w;
      wa[j][0] = wq.x; wa[j][1] = wq.y; wa[j][2] = wq.z; wa[j][3] = wq.w;
    }
#pragma unroll
    for (int n = 0; n < 4; ++n) {
      const int col = ccol0 + n * 16;
      const float ub = bias[col];
#pragma unroll
      for (int j = 0; j < 4; ++j) {
        float g = wa[j][0] * gates[(size_t)ia[j][0] * DFF + col]
                + wa[j][1] * gates[(size_t)ia[j][1] * DFF + col]
                + wa[j][2] * gates[(size_t)ia[j][2] * DFF + col]
                + wa[j][3] * gates[(size_t)ia[j][3] * DFF + col];
        const float u   = acc[m][n][j] + ub;
        const float val = u * (1.f / (1.f + __expf(-g)));
        const float h   = 0.5f * val * (1.f + erff(val * 0.70710678118654752f));
        H[(size_t)(rbase + j) * DFF + col] = f2bf(h);
      }
    }
  }
}

// ---- GEMM2: out[8192][1024] = H[8192][4096] @ dwb[1024][4096]^T + dnb
// tile 256x128, waves 4x2 (wave out 64x64), NT=64, LDS 2*48KB.
__global__ __launch_bounds__(512, 2) void gemm2_kernel(
    const unsigned short* __restrict__ A,
    const unsigned short* __restrict__ Bm,
    const float* __restrict__ bias,
    float* __restrict__ O)
{
  extern __shared__ char smem[];
  constexpr int K_ = 4096, NT = 64;
  const int tid = threadIdx.x, lane = tid & 63, wid = tid >> 6;
  const int wr = wid >> 1, wc = wid & 1;
  const int cpx = gridDim.x >> 3;
  const int swzb = ((int)blockIdx.x & 7) * cpx + ((int)blockIdx.x >> 3);
  const int brow = swzb >> 3, bcol = swzb & 7;

  const unsigned short* Ab = A  + (size_t)brow * 256 * K_;
  const unsigned short* Bb = Bm + (size_t)bcol * 128 * K_;

  const int soff0 = (wid * 8 + (lane >> 3)) * K_ + ((lane & 7) ^ (lane >> 3)) * 8;
  const int soff1 = soff0 + 64 * K_;
  const int paoff = (wr >> 1) * 16384 + (wr & 1) * 8192 + (lane & 15) * 128;
  const int pboff = 32768 + wc * 8192 + (lane & 15) * 128;
  const int sw0 = ((lane >> 4) ^ (lane & 7)) * 16;
  const int sw1 = ((4 + (lane >> 4)) ^ (lane & 7)) * 16;

  f32x4 acc[4][4];
#pragma unroll
  for (int m = 0; m < 4; ++m)
#pragma unroll
    for (int n = 0; n < 4; ++n) acc[m][n] = (f32x4){0.f, 0.f, 0.f, 0.f};

  // prologue: stage tile 0 into buf0 (A0, A1, B)
  STAGEH(Ab,            0)
  STAGEH(Ab + 128 * K_, 16384)
  STAGEH(Bb,            32768)
  asm volatile("s_waitcnt vmcnt(0)" ::: "memory");
  __builtin_amdgcn_s_barrier();

#define KT2_BODY(BB, SB, GUARD, KT)                                         \
  {                                                                         \
    const char* pa = smem + (BB) + paoff;                                   \
    const char* pb = smem + (BB) + pboff;                                   \
    const unsigned short* At = Ab + ((KT) + 1) * 64;                        \
    const unsigned short* Bt = Bb + ((KT) + 1) * 64;                        \
    bf16x8 af[4], bf[4];                                                    \
    /* q0: ks0 frags; stage all 3 next halves */                            \
    RD4(af, pa + sw0) RD4(bf, pb + sw0)                                     \
    if (GUARD) { STAGEH(At, (SB) + 0) STAGEH(At + 128 * K_, (SB) + 16384)   \
                 STAGEH(Bt, (SB) + 32768) }                                 \
    PHSYNC(0) MF16(0, af, bf) PHEND                                         \
    /* q1: ks1 frags; drain */                                              \
    RD4(af, pa + sw1) RD4(bf, pb + sw1)                                     \
    PHSYNC(1) MF16(0, af, bf) PHEND                                         \
  }

#pragma unroll 1
  for (int k2 = 0; k2 < NT / 2; ++k2) {
    const int kt0 = k2 * 2;
    KT2_BODY(0,     49152, true,            kt0)
    KT2_BODY(49152, 0,     (k2 < NT/2 - 1), kt0 + 1)
  }
#undef KT2_BODY

  const int crow0 = brow * 256 + wr * 64;
  const int ccol0 = bcol * 128 + wc * 64 + (lane & 15);
  const int rsub  = (lane >> 4) * 4;
#pragma unroll
  for (int m = 0; m < 4; ++m) {
    const int rbase = crow0 + m * 16 + rsub;
#pragma unroll
    for (int n = 0; n < 4; ++n) {
      const int col = ccol0 + n * 16;
      const float db = bias[col];
#pragma unroll
      for (int j = 0; j < 4; ++j)
        O[(size_t)(rbase + j) * DM + col] = acc[m][n][j] + db;
    }
  }
}

// ---------------------------------------------------------------------- launch
extern "C" void kernel_launch(void* const* d_in, const int* in_sizes, int n_in,
                              void* d_out, int out_size, void* d_ws, size_t ws_size,
                              hipStream_t stream) {
  const float* x     = (const float*)d_in[0];
  const float* tw    = (const float*)d_in[3];
  const float* sn    = (const float*)d_in[4];
  const float* pq    = (const float*)d_in[5];
  const float* gates = (const float*)d_in[6];
  const float* upw   = (const float*)d_in[7];
  const float* upb   = (const float*)d_in[8];
  const float* dnw   = (const float*)d_in[9];
  const float* dnb   = (const float*)d_in[10];
  float* out = (float*)d_out;

  char* p = (char*)d_ws;
  unsigned short* xb  = (unsigned short*)p; p += (size_t)R_ * DM * 2;
  unsigned short* uwb = (unsigned short*)p; p += (size_t)DFF * DM * 2;
  unsigned short* dwb = (unsigned short*)p; p += (size_t)DM * DFF * 2;
  unsigned short* H   = (unsigned short*)p; p += (size_t)R_ * DFF * 2;
  int*   pidx = (int*)p;   p += (size_t)R_ * 4 * sizeof(int);
  float* pwt  = (float*)p; p += (size_t)R_ * 4 * sizeof(float);
  float* vbuf = (float*)p; p += (size_t)R_ * DM * sizeof(float);

  cvt_bf16_kernel<<<(R_ * DM / 8) / 256, 256, 0, stream>>>(x, xb, R_ * DM / 8);
  cvt_bf16_kernel<<<(DFF * DM / 8) / 256, 256, 0, stream>>>(upw, uwb, DFF * DM / 8);
  cvt_bf16_kernel<<<(DM * DFF / 8) / 256, 256, 0, stream>>>(dnw, dwb, DM * DFF / 8);

  vcomp_kernel<<<R_, 256, 0, stream>>>(sn, tw, vbuf);
  score_kernel<<<R_ / 16, 256, 0, stream>>>(vbuf, pq, pidx, pwt);

  hipFuncSetAttribute((const void*)gemm1_kernel,
                      hipFuncAttributeMaxDynamicSharedMemorySize, 131072);
  hipFuncSetAttribute((const void*)gemm2_kernel,
                      hipFuncAttributeMaxDynamicSharedMemorySize, 98304);

  gemm1_kernel<<<(R_ / 256) * (DFF / 256), 512, 131072, stream>>>(
      xb, uwb, upb, pidx, pwt, gates, H);
  gemm2_kernel<<<(R_ / 256) * (DM / 128), 512, 98304, stream>>>(
      H, dwb, dnb, out);
}

// Round 6
// 369.153 us; speedup vs baseline: 1.1090x; 1.1090x over previous
//
#include <hip/hip_runtime.h>
#include <hip/hip_bf16.h>
#include <math.h>

// Problem constants
#define R_   8192    // B*S rows
#define DM   1024    // d_model
#define DFF  4096    // d_ff
#define NP   64      // n_patterns
#define KN   8       // K neurons

typedef __bf16 bf16x8 __attribute__((ext_vector_type(8)));
typedef float  f32x4  __attribute__((ext_vector_type(4)));

__device__ __forceinline__ unsigned short f2bf(float f) {
  union { float f; unsigned u; } v; v.f = f;
  unsigned u = v.u;
  return (unsigned short)((u + 0x7FFFu + ((u >> 16) & 1u)) >> 16);
}

__device__ __forceinline__ float dot4(const float4 a, const float4 b) {
  return a.x * b.x + a.y * b.y + a.z * b.z + a.w * b.w;
}

__device__ __forceinline__ void fma4(float4& a, float w, const float4 s) {
  a.x += w * s.x; a.y += w * s.y; a.z += w * s.z; a.w += w * s.w;
}

// ---------------------------------------------------------------- f32 -> bf16
__global__ __launch_bounds__(256) void cvt_bf16_kernel(
    const float* __restrict__ in, unsigned short* __restrict__ out, int n8) {
  int i = blockIdx.x * 256 + threadIdx.x;
  if (i >= n8) return;
  const float4* p = (const float4*)in + (size_t)i * 2;
  float4 a = p[0], b = p[1];
  uint4 r;
  r.x = (unsigned)f2bf(a.x) | ((unsigned)f2bf(a.y) << 16);
  r.y = (unsigned)f2bf(a.z) | ((unsigned)f2bf(a.w) << 16);
  r.z = (unsigned)f2bf(b.x) | ((unsigned)f2bf(b.y) << 16);
  r.w = (unsigned)f2bf(b.z) | ((unsigned)f2bf(b.w) << 16);
  ((uint4*)out)[i] = r;
}

// -------------------------------------------------------------- v materialize
__global__ __launch_bounds__(256) void vcomp_kernel(
    const float* __restrict__ sn,    // [R_][8][1024]
    const float* __restrict__ tw,    // [R_][8]
    float* __restrict__ v)           // [R_][1024]
{
  const int r = blockIdx.x;
  const int t = threadIdx.x;
  float w[KN];
#pragma unroll
  for (int k = 0; k < KN; ++k) w[k] = tw[(size_t)r * KN + k];
  const float* base = sn + (size_t)r * (KN * DM) + t * 4;
  float4 a = {0.f, 0.f, 0.f, 0.f};
#pragma unroll
  for (int k = 0; k < KN; ++k) fma4(a, w[k], *(const float4*)(base + k * DM));
  *(float4*)(v + (size_t)r * DM + t * 4) = a;
}

// ------------------------------------------------- pattern scores/topk/softmax
__global__ __launch_bounds__(256, 2) void score_kernel(
    const float* __restrict__ v,     // [R_][1024]
    const float* __restrict__ pq,    // [64][1024]
    int*   __restrict__ out_idx,     // [R_][4]
    float* __restrict__ out_w)       // [R_][4]
{
  const int lane = threadIdx.x & 63;
  const int wave = threadIdx.x >> 6;
  const int pos0 = (blockIdx.x * 4 + wave) * 4;

  float4 vr[4][4];
#pragma unroll
  for (int p = 0; p < 4; ++p) {
    const float4* s = (const float4*)(v + (size_t)(pos0 + p) * DM + lane * 16);
    vr[p][0] = s[0]; vr[p][1] = s[1]; vr[p][2] = s[2]; vr[p][3] = s[3];
  }

  float sreg[4];
#pragma unroll 1
  for (int pat = 0; pat < NP; ++pat) {
    const float4* q = (const float4*)(pq + pat * DM + lane * 16);
    const float4 q0 = q[0], q1 = q[1], q2 = q[2], q3 = q[3];
    float part[4];
#pragma unroll
    for (int p = 0; p < 4; ++p)
      part[p] = dot4(q0, vr[p][0]) + dot4(q1, vr[p][1]) +
                dot4(q2, vr[p][2]) + dot4(q3, vr[p][3]);
#pragma unroll
    for (int off = 32; off >= 1; off >>= 1) {
#pragma unroll
      for (int p = 0; p < 4; ++p)
        part[p] += __shfl_xor(part[p], off, 64);
    }
    if (lane == pat) {
#pragma unroll
      for (int p = 0; p < 4; ++p) sreg[p] = part[p] * 0.03125f; // /sqrt(1024)
    }
  }

#pragma unroll
  for (int p = 0; p < 4; ++p) {
    float cur = sreg[p];
    float m0, m1, m2, m3; int i0, i1, i2, i3;
#define ARGMAX_STEP(MV, MI)                                   \
    {                                                         \
      float bv = cur; int bi = lane;                          \
      _Pragma("unroll")                                       \
      for (int off = 32; off >= 1; off >>= 1) {               \
        float ov = __shfl_xor(bv, off, 64);                   \
        int   oi = __shfl_xor(bi, off, 64);                   \
        if (ov > bv || (ov == bv && oi < bi)) { bv = ov; bi = oi; } \
      }                                                       \
      MV = bv; MI = bi;                                       \
      if (lane == bi) cur = -3.0e38f;                         \
    }
    ARGMAX_STEP(m0, i0) ARGMAX_STEP(m1, i1) ARGMAX_STEP(m2, i2) ARGMAX_STEP(m3, i3)
#undef ARGMAX_STEP
    const float e1 = __expf(m1 - m0), e2 = __expf(m2 - m0), e3 = __expf(m3 - m0);
    const float inv = 1.f / (1.f + e1 + e2 + e3);
    if (lane < 4) {
      const int r = pos0 + p;
      const int myi = (lane == 0) ? i0 : (lane == 1) ? i1 : (lane == 2) ? i2 : i3;
      const float mye = (lane == 0) ? 1.f : (lane == 1) ? e1 : (lane == 2) ? e2 : e3;
      out_idx[r * 4 + lane] = myi;
      out_w[r * 4 + lane] = mye * inv;
    }
  }
}

// ------------------------------------------------------------ GEMM machinery
__device__ __forceinline__ void gll16(const void* g, void* l) {
  __builtin_amdgcn_global_load_lds(
      (const __attribute__((address_space(1))) unsigned int*)g,
      (__attribute__((address_space(3))) unsigned int*)l, 16, 0, 0);
}

// Shared design (both GEMMs): 256 thr / 4 waves (2x2), wave-tile 128x64
// (gemm1) or 64x64 (gemm2); BK=32; XOR slot swizzle: element (row, 16B-slot
// ks of 4) stored at LDS slot ks ^ (row&3).  Stage (linear global_load_lds):
// lane pre-swizzles global slot (lane&3)^((lane>>2)&3); frag read slot
// (lane>>4)^(lane&3).  2 blocks/CU (the overlap lever): LDS <= 72KB, VGPR
// <= 256.  Counted vmcnt: every wait is for loads issued >=2-3 phases ago.

#define LGKM0 asm volatile("s_waitcnt lgkmcnt(0)" ::: "memory")
#define VMC(N) asm volatile("s_waitcnt vmcnt(%0)" ::"i"(N) : "memory")

// ---- GEMM1: H = gelu_gate(xb[8192][1024] @ uwb[4096][1024]^T)
// block-tile 256x128, ring-3 LDS (3 x 24KB), 2 phases/K-tile, NT=32.
// Ledger: ph0 stages A(j+2) into buf(j-1) (its reads drained pre-barrier at
// [j-1,ph1]); ph1 stages B(j+3) into buf j (B read only at [j,ph0]).
// vmcnt(6) at ph1 leaves A(j+2)+B(j+3) in flight -> confirms A(j+1) (issued
// [j-1,ph0], 3 phases old) and B(j+1) just before [j+1,ph0] reads them.
__global__ __launch_bounds__(256, 2) void gemm1_kernel(
    const unsigned short* __restrict__ A,
    const unsigned short* __restrict__ Bm,
    const float* __restrict__ bias,
    const int*   __restrict__ pidx,
    const float* __restrict__ pwt,
    const float* __restrict__ gates,
    unsigned short* __restrict__ H)
{
  extern __shared__ char smem[];
  constexpr int K_ = 1024, NT = 32;
  const int tid = threadIdx.x, lane = tid & 63, wid = tid >> 6;
  const int wr = wid >> 1, wc = wid & 1;
  const int cpx = gridDim.x >> 3;
  const int swzb = ((int)blockIdx.x & 7) * cpx + ((int)blockIdx.x >> 3);
  const int brow = swzb >> 5, bcol = swzb & 31;   // 32x32 grid

  const unsigned short* Ab = A  + (size_t)brow * 256 * K_;
  const unsigned short* Bb = Bm + (size_t)bcol * 128 * K_;

  // staging offsets (element units)
  const int aSrc = (wid * 16 + (lane >> 2)) * K_ +
                   (((lane & 3) ^ ((lane >> 2) & 3)) * 8);
  const int ldsSt = wid * 1024;
  // frag read offsets (bytes within region)
  const int laneRd = (lane & 15) * 64 + (((lane >> 4) ^ (lane & 3)) * 16);
  const int aRd = wr * 8192 + laneRd;            // + ph*4096 + m*1024
  const int bRd = 16384 + wc * 4096 + laneRd;    // + n*1024

  f32x4 acc[8][4];
#pragma unroll
  for (int m = 0; m < 8; ++m)
#pragma unroll
    for (int n = 0; n < 4; ++n) acc[m][n] = (f32x4){0.f, 0.f, 0.f, 0.f};

#define G1_STA(BO, PG) { _Pragma("unroll") for (int i_ = 0; i_ < 4; ++i_)     \
    gll16((PG) + i_ * 64 * K_ + aSrc, smem + (BO) + i_ * 4096 + ldsSt); }
#define G1_STB(BO, PG) { _Pragma("unroll") for (int i_ = 0; i_ < 2; ++i_)     \
    gll16((PG) + i_ * 64 * K_ + aSrc, smem + (BO) + 16384 + i_ * 4096 + ldsSt); }

  // prologue: A0 B0 A1 B1 B2 (14 loads); confirm A0,B0
  G1_STA(0, Ab)           G1_STB(0, Bb)
  G1_STA(24576, Ab + 32)  G1_STB(24576, Bb + 32)
  G1_STB(49152, Bb + 64)
  VMC(8);
  __builtin_amdgcn_s_barrier();

  int o0 = 0, o1 = 24576, o2 = 49152;
#pragma unroll 1
  for (int j = 0; j < NT; ++j) {
    bf16x8 a[4], b[4];
    // ---- ph0: A-mh0 + B frags; stage A(j+2)
    {
      const char* pa = smem + o0 + aRd;
      const char* pb = smem + o0 + bRd;
#pragma unroll
      for (int m = 0; m < 4; ++m) a[m] = *(const bf16x8*)(pa + m * 1024);
#pragma unroll
      for (int n = 0; n < 4; ++n) b[n] = *(const bf16x8*)(pb + n * 1024);
    }
    if (j < NT - 2) G1_STA(o2, Ab + (j + 2) * 32)
    LGKM0;
    __builtin_amdgcn_s_barrier();
    __builtin_amdgcn_s_setprio(1);
#pragma unroll
    for (int m = 0; m < 4; ++m)
#pragma unroll
      for (int n = 0; n < 4; ++n)
        acc[m][n] = __builtin_amdgcn_mfma_f32_16x16x32_bf16(a[m], b[n], acc[m][n], 0, 0, 0);
    __builtin_amdgcn_s_setprio(0);
    // ---- ph1: A-mh1 frags; stage B(j+3); counted vmcnt
    {
      const char* pa = smem + o0 + aRd + 4096;
#pragma unroll
      for (int m = 0; m < 4; ++m) a[m] = *(const bf16x8*)(pa + m * 1024);
    }
    if (j < NT - 3) G1_STB(o0, Bb + (j + 3) * 32)
    LGKM0;
    if (j < NT - 2) { VMC(6); } else { VMC(0); }
    __builtin_amdgcn_s_barrier();
    __builtin_amdgcn_s_setprio(1);
#pragma unroll
    for (int m = 0; m < 4; ++m)
#pragma unroll
      for (int n = 0; n < 4; ++n)
        acc[4 + m][n] = __builtin_amdgcn_mfma_f32_16x16x32_bf16(a[m], b[n], acc[4 + m][n], 0, 0, 0);
    __builtin_amdgcn_s_setprio(0);
    const int t = o0; o0 = o1; o1 = o2; o2 = t;
  }
#undef G1_STA
#undef G1_STB

  // epilogue: C/D layout col = lane&15, row = (lane>>4)*4 + j
  const int crow0 = brow * 256 + wr * 128;
  const int ccol0 = bcol * 128 + wc * 64 + (lane & 15);
  const int rsub  = (lane >> 4) * 4;
#pragma unroll
  for (int m = 0; m < 8; ++m) {
    const int rbase = crow0 + m * 16 + rsub;
    int   ia[4][4];
    float wa[4][4];
#pragma unroll
    for (int j = 0; j < 4; ++j) {
      const int4   iq = *(const int4*)(pidx + (size_t)(rbase + j) * 4);
      const float4 wq = *(const float4*)(pwt + (size_t)(rbase + j) * 4);
      ia[j][0] = iq.x; ia[j][1] = iq.y; ia[j][2] = iq.z; ia[j][3] = iq.w;
      wa[j][0] = wq.x; wa[j][1] = wq.y; wa[j][2] = wq.z; wa[j][3] = wq.w;
    }
#pragma unroll
    for (int n = 0; n < 4; ++n) {
      const int col = ccol0 + n * 16;
      const float ub = bias[col];
#pragma unroll
      for (int j = 0; j < 4; ++j) {
        float g = wa[j][0] * gates[(size_t)ia[j][0] * DFF + col]
                + wa[j][1] * gates[(size_t)ia[j][1] * DFF + col]
                + wa[j][2] * gates[(size_t)ia[j][2] * DFF + col]
                + wa[j][3] * gates[(size_t)ia[j][3] * DFF + col];
        const float u   = acc[m][n][j] + ub;
        const float val = u * (1.f / (1.f + __expf(-g)));
        const float h   = 0.5f * val * (1.f + erff(val * 0.70710678118654752f));
        H[(size_t)(rbase + j) * DFF + col] = f2bf(h);
      }
    }
  }
}

// ---- GEMM2: out = H[8192][4096] @ dwb[1024][4096]^T + dnb
// block-tile 128x128 (grid 512 -> 2 blocks/CU), ring-4 LDS (4 x 16KB),
// 1 phase/K-tile, NT=128.  Stage tile j+3 into buf(j-1) (read ended [j-1]);
// vmcnt(8) leaves stages of j and j-1 in flight -> confirms (j-2)'s batch
// (= tile j+1 data) just before [j+1] reads it; waits ~2 tiles-old loads.
__global__ __launch_bounds__(256, 2) void gemm2_kernel(
    const unsigned short* __restrict__ A,
    const unsigned short* __restrict__ Bm,
    const float* __restrict__ bias,
    float* __restrict__ O)
{
  extern __shared__ char smem[];
  constexpr int K_ = 4096, NT = 128;
  const int tid = threadIdx.x, lane = tid & 63, wid = tid >> 6;
  const int wr = wid >> 1, wc = wid & 1;
  const int cpx = gridDim.x >> 3;
  const int swzb = ((int)blockIdx.x & 7) * cpx + ((int)blockIdx.x >> 3);
  const int brow = swzb >> 3, bcol = swzb & 7;   // 64x8 grid

  const unsigned short* Ab = A  + (size_t)brow * 128 * K_;
  const unsigned short* Bb = Bm + (size_t)bcol * 128 * K_;

  const int aSrc = (wid * 16 + (lane >> 2)) * K_ +
                   (((lane & 3) ^ ((lane >> 2) & 3)) * 8);
  const int ldsSt = wid * 1024;
  const int laneRd = (lane & 15) * 64 + (((lane >> 4) ^ (lane & 3)) * 16);
  const int aRd = wr * 4096 + laneRd;           // + m*1024
  const int bRd = 8192 + wc * 4096 + laneRd;    // + n*1024

  f32x4 acc[4][4];
#pragma unroll
  for (int m = 0; m < 4; ++m)
#pragma unroll
    for (int n = 0; n < 4; ++n) acc[m][n] = (f32x4){0.f, 0.f, 0.f, 0.f};

#define G2_ST(BO, PGA, PGB) {                                                 \
    _Pragma("unroll") for (int i_ = 0; i_ < 2; ++i_)                          \
      gll16((PGA) + i_ * 64 * K_ + aSrc, smem + (BO) + i_ * 4096 + ldsSt);    \
    _Pragma("unroll") for (int i_ = 0; i_ < 2; ++i_)                          \
      gll16((PGB) + i_ * 64 * K_ + aSrc, smem + (BO) + 8192 + i_ * 4096 + ldsSt); }

  // prologue: tiles 0,1,2 (12 loads); confirm tile 0
  G2_ST(0,     Ab,      Bb)
  G2_ST(16384, Ab + 32, Bb + 32)
  G2_ST(32768, Ab + 64, Bb + 64)
  VMC(8);
  __builtin_amdgcn_s_barrier();

  int o0 = 0, o1 = 16384, o2 = 32768, o3 = 49152;
#pragma unroll 1
  for (int j = 0; j < NT; ++j) {
    bf16x8 a[4], b[4];
    {
      const char* pa = smem + o0 + aRd;
      const char* pb = smem + o0 + bRd;
#pragma unroll
      for (int m = 0; m < 4; ++m) a[m] = *(const bf16x8*)(pa + m * 1024);
#pragma unroll
      for (int n = 0; n < 4; ++n) b[n] = *(const bf16x8*)(pb + n * 1024);
    }
    if (j < NT - 3) G2_ST(o3, Ab + (j + 3) * 32, Bb + (j + 3) * 32)
    LGKM0;
    if (j < NT - 3)      { VMC(8); }
    else if (j == NT - 3){ VMC(4); }
    else                 { VMC(0); }
    __builtin_amdgcn_s_barrier();
    __builtin_amdgcn_s_setprio(1);
#pragma unroll
    for (int m = 0; m < 4; ++m)
#pragma unroll
      for (int n = 0; n < 4; ++n)
        acc[m][n] = __builtin_amdgcn_mfma_f32_16x16x32_bf16(a[m], b[n], acc[m][n], 0, 0, 0);
    __builtin_amdgcn_s_setprio(0);
    const int t = o0; o0 = o1; o1 = o2; o2 = o3; o3 = t;
  }
#undef G2_ST

  const int crow0 = brow * 128 + wr * 64;
  const int ccol0 = bcol * 128 + wc * 64 + (lane & 15);
  const int rsub  = (lane >> 4) * 4;
#pragma unroll
  for (int m = 0; m < 4; ++m) {
    const int rbase = crow0 + m * 16 + rsub;
#pragma unroll
    for (int n = 0; n < 4; ++n) {
      const int col = ccol0 + n * 16;
      const float db = bias[col];
#pragma unroll
      for (int j = 0; j < 4; ++j)
        O[(size_t)(rbase + j) * DM + col] = acc[m][n][j] + db;
    }
  }
}

// ---------------------------------------------------------------------- launch
extern "C" void kernel_launch(void* const* d_in, const int* in_sizes, int n_in,
                              void* d_out, int out_size, void* d_ws, size_t ws_size,
                              hipStream_t stream) {
  const float* x     = (const float*)d_in[0];
  const float* tw    = (const float*)d_in[3];
  const float* sn    = (const float*)d_in[4];
  const float* pq    = (const float*)d_in[5];
  const float* gates = (const float*)d_in[6];
  const float* upw   = (const float*)d_in[7];
  const float* upb   = (const float*)d_in[8];
  const float* dnw   = (const float*)d_in[9];
  const float* dnb   = (const float*)d_in[10];
  float* out = (float*)d_out;

  char* p = (char*)d_ws;
  unsigned short* xb  = (unsigned short*)p; p += (size_t)R_ * DM * 2;
  unsigned short* uwb = (unsigned short*)p; p += (size_t)DFF * DM * 2;
  unsigned short* dwb = (unsigned short*)p; p += (size_t)DM * DFF * 2;
  unsigned short* H   = (unsigned short*)p; p += (size_t)R_ * DFF * 2;
  int*   pidx = (int*)p;   p += (size_t)R_ * 4 * sizeof(int);
  float* pwt  = (float*)p; p += (size_t)R_ * 4 * sizeof(float);
  float* vbuf = (float*)p; p += (size_t)R_ * DM * sizeof(float);

  cvt_bf16_kernel<<<(R_ * DM / 8) / 256, 256, 0, stream>>>(x, xb, R_ * DM / 8);
  cvt_bf16_kernel<<<(DFF * DM / 8) / 256, 256, 0, stream>>>(upw, uwb, DFF * DM / 8);
  cvt_bf16_kernel<<<(DM * DFF / 8) / 256, 256, 0, stream>>>(dnw, dwb, DM * DFF / 8);

  vcomp_kernel<<<R_, 256, 0, stream>>>(sn, tw, vbuf);
  score_kernel<<<R_ / 16, 256, 0, stream>>>(vbuf, pq, pidx, pwt);

  hipFuncSetAttribute((const void*)gemm1_kernel,
                      hipFuncAttributeMaxDynamicSharedMemorySize, 73728);
  hipFuncSetAttribute((const void*)gemm2_kernel,
                      hipFuncAttributeMaxDynamicSharedMemorySize, 65536);

  // gemm1: 32x32 = 1024 blocks; gemm2: 64x8 = 512 blocks (both 2 blocks/CU)
  gemm1_kernel<<<(R_ / 256) * (DFF / 128), 256, 73728, stream>>>(
      xb, uwb, upb, pidx, pwt, gates, H);
  gemm2_kernel<<<(R_ / 128) * (DM / 128), 256, 65536, stream>>>(
      H, dwb, dnb, out);
}